// Round 1
// baseline (5251.038 us; speedup 1.0000x reference)
//
#include <hip/hip_runtime.h>
#include <math.h>

namespace {
constexpr int kBL = 16 * 2048;   // B * L rows
constexpr int kH = 256;          // hidden size
constexpr int kNOut = 12;        // recurrent steps / outputs per row
constexpr int kR = 64;           // rows per block (= lanes per wave)
constexpr int kNW = 8;           // waves per block
constexpr int kThreads = kNW * 64;
constexpr int kStride = kH + 4;  // 260 dwords: bank-stride 4, balanced for b128
}

__global__ __launch_bounds__(kThreads, 2)
void rbq_fp32_kernel(const float* __restrict__ emb,    // [BL][H]
                     const float* __restrict__ w_ih,   // [3H]
                     const float* __restrict__ w_hh,   // [3H][H]
                     const float* __restrict__ b_ih,   // [3H]
                     const float* __restrict__ b_hh,   // [3H]
                     const float* __restrict__ w_out,  // [H]
                     const float* __restrict__ b_out,  // [1]
                     float* __restrict__ out) {        // [2][BL][NOut]
  __shared__ float hbuf[2][kR][kStride];  // h_in = h + e, double-buffered
  __shared__ float osc[kR][kNW];          // per-wave partial of o
  __shared__ float xq[kR];                // quantized feedback x

  const int lane = threadIdx.x & 63;
  // wave index is uniform; force SGPR so w_hh/bias addressing stays scalar.
  const int wv = __builtin_amdgcn_readfirstlane((int)(threadIdx.x >> 6));
  const int i_base = wv * 32;             // this wave's 32 hidden units
  const int row0 = blockIdx.x * kR;

  // init: h0 = 0 -> h_in = e; x0 = 0
  {
    const float* eb = emb + (size_t)row0 * kH;
    for (int f4 = threadIdx.x; f4 < kR * (kH / 4); f4 += kThreads) {
      const int r = f4 >> 6;              // kH/4 = 64 float4 per row
      const int c = (f4 & 63) << 2;
      const float4 v = *reinterpret_cast<const float4*>(eb + (size_t)r * kH + c);
      *reinterpret_cast<float4*>(&hbuf[0][r][c]) = v;
    }
    if (threadIdx.x < kR) xq[threadIdx.x] = 0.0f;
  }
  __syncthreads();

  const float bo = b_out[0];
  const float* __restrict__ erow = emb + (size_t)(row0 + lane) * kH;
  const size_t q_off = (size_t)kBL * kNOut;

  for (int step = 0; step < kNOut; ++step) {
    const int cur = step & 1;
    const float(*__restrict__ hin)[kStride] = hbuf[cur];
    float(*__restrict__ hout)[kStride] = hbuf[cur ^ 1];
    const float x = xq[lane];
    float opart = 0.0f;

#pragma unroll 1
    for (int c = 0; c < 8; ++c) {
      const int i0 = i_base + c * 4;
      float ar[4] = {0.f, 0.f, 0.f, 0.f};
      float az[4] = {0.f, 0.f, 0.f, 0.f};
      float an[4] = {0.f, 0.f, 0.f, 0.f};
      const float* __restrict__ wr = w_hh + (size_t)i0 * kH;
      const float* __restrict__ wz = w_hh + (size_t)(kH + i0) * kH;
      const float* __restrict__ wn = w_hh + (size_t)(2 * kH + i0) * kH;
#pragma unroll 2
      for (int k = 0; k < kH; k += 4) {
        const float4 h4 = *reinterpret_cast<const float4*>(&hin[lane][k]);
#pragma unroll
        for (int ii = 0; ii < 4; ++ii) {
          const float* wrp = wr + ii * kH + k;
          const float* wzp = wz + ii * kH + k;
          const float* wnp = wn + ii * kH + k;
          ar[ii] += h4.x * wrp[0]; ar[ii] += h4.y * wrp[1];
          ar[ii] += h4.z * wrp[2]; ar[ii] += h4.w * wrp[3];
          az[ii] += h4.x * wzp[0]; az[ii] += h4.y * wzp[1];
          az[ii] += h4.z * wzp[2]; az[ii] += h4.w * wzp[3];
          an[ii] += h4.x * wnp[0]; an[ii] += h4.y * wnp[1];
          an[ii] += h4.z * wnp[2]; an[ii] += h4.w * wnp[3];
        }
      }
      const float4 e4 = *reinterpret_cast<const float4*>(erow + i0);
      const float ev[4] = {e4.x, e4.y, e4.z, e4.w};
      float hn4[4];
#pragma unroll
      for (int ii = 0; ii < 4; ++ii) {
        const int i = i0 + ii;
        const float ghr = ar[ii] + b_hh[i];
        const float ghz = az[ii] + b_hh[kH + i];
        const float ghn = an[ii] + b_hh[2 * kH + i];
        const float gr = x * w_ih[i] + b_ih[i] + ghr;
        const float gz = x * w_ih[kH + i] + b_ih[kH + i] + ghz;
        const float gn = x * w_ih[2 * kH + i] + b_ih[2 * kH + i];
        const float rg = 1.0f / (1.0f + expf(-gr));
        const float zg = 1.0f / (1.0f + expf(-gz));
        const float ng = tanhf(gn + rg * ghn);
        const float hprev = hin[lane][i];
        const float hn = (1.0f - zg) * ng + zg * hprev;
        opart += hn * w_out[i];
        hn4[ii] = hn + ev[ii];   // next step's h_in = h_new + e
      }
      *reinterpret_cast<float4*>(&hout[lane][i0]) =
          make_float4(hn4[0], hn4[1], hn4[2], hn4[3]);
    }
    osc[lane][wv] = opart;
    __syncthreads();
    if (threadIdx.x < kR) {
      const int r = threadIdx.x;
      float s = 0.f;
#pragma unroll
      for (int w2 = 0; w2 < kNW; ++w2) s += osc[r][w2];
      const float o = s + bo;
      const float q = o > 0.0f ? 1.0f : -1.0f;
      const size_t gr = (size_t)row0 + r;
      out[gr * kNOut + step] = o;
      out[q_off + gr * kNOut + step] = q;
      xq[r] = q;
    }
    __syncthreads();
  }
}

extern "C" void kernel_launch(void* const* d_in, const int* in_sizes, int n_in,
                              void* d_out, int out_size, void* d_ws, size_t ws_size,
                              hipStream_t stream) {
  (void)in_sizes; (void)n_in; (void)d_ws; (void)ws_size; (void)out_size;
  const float* emb = (const float*)d_in[0];
  const float* w_ih = (const float*)d_in[1];
  const float* w_hh = (const float*)d_in[2];
  const float* b_ih = (const float*)d_in[3];
  const float* b_hh = (const float*)d_in[4];
  const float* w_out = (const float*)d_in[5];
  const float* b_out = (const float*)d_in[6];
  rbq_fp32_kernel<<<kBL / kR, kThreads, 0, stream>>>(
      emb, w_ih, w_hh, b_ih, b_hh, w_out, b_out, (float*)d_out);
}

// Round 2
// 763.798 us; speedup vs baseline: 6.8749x; 6.8749x over previous
//
#include <hip/hip_runtime.h>
#include <math.h>

namespace {
constexpr int kBL = 16 * 2048;
constexpr int kH = 256;
constexpr int kNOut = 12;
constexpr int kRows = 64;          // rows per block
constexpr int kThreads = 512;      // 8 waves
constexpr int kAStride = 264;      // bf16 elems per LDS row (256 + 8 pad)
constexpr int kWhh = 3 * kH * kH;  // 196608
}

using short8 = __attribute__((ext_vector_type(8))) short;
using f32x4 = __attribute__((ext_vector_type(4))) float;

__device__ inline void bsplit(float v, short& h, short& l) {
  unsigned u = __float_as_uint(v);
  unsigned rh = u + 0x7FFFu + ((u >> 16) & 1u);   // RNE to bf16
  h = (short)(rh >> 16);
  float hf = __uint_as_float(rh & 0xFFFF0000u);
  float r = v - hf;                                // exact (two-term split)
  unsigned u2 = __float_as_uint(r);
  unsigned rl = u2 + 0x7FFFu + ((u2 >> 16) & 1u);
  l = (short)(rl >> 16);
}

// ---- prep: split w_hh [768][256] fp32 -> bf16 hi/lo planes in d_ws ----
__global__ void split_whh_kernel(const float* __restrict__ w,
                                 short* __restrict__ hi, short* __restrict__ lo) {
  const int i = (blockIdx.x * 256 + threadIdx.x) * 4;
  const float4 v = *reinterpret_cast<const float4*>(w + i);
  short4 h4, l4;
  bsplit(v.x, h4.x, l4.x);
  bsplit(v.y, h4.y, l4.y);
  bsplit(v.z, h4.z, l4.z);
  bsplit(v.w, h4.w, l4.w);
  *reinterpret_cast<short4*>(hi + i) = h4;
  *reinterpret_cast<short4*>(lo + i) = l4;
}

__global__ __launch_bounds__(kThreads, 2)
void rbq_mfma_kernel(const float* __restrict__ emb,    // [BL][256]
                     const float* __restrict__ w_ih,   // [768]
                     const float* __restrict__ b_ih,   // [768]
                     const float* __restrict__ b_hh,   // [768]
                     const float* __restrict__ w_out,  // [256]
                     const float* __restrict__ b_out,  // [1]
                     const short* __restrict__ Bhi,    // [768][256] bf16
                     const short* __restrict__ Blo,
                     float* __restrict__ out) {        // [2][BL][12]
  __shared__ short Ah[kRows][kAStride];   // h_in hi (bf16 bits)
  __shared__ short Al[kRows][kAStride];   // h_in lo
  __shared__ float osc[kRows][9];         // per-wave o partials (padded)
  __shared__ float xq[kRows];             // quantized feedback

  const int tid = threadIdx.x;
  const int lane = tid & 63;
  const int wv = __builtin_amdgcn_readfirstlane(tid >> 6);  // 0..7: owns H-cols wv*32..+32
  const int grp = lane >> 4;   // 0..3
  const int c16 = lane & 15;
  const int row0 = blockIdx.x * kRows;

  // per-lane column constants: j_t = wv*32 + t*16 + c16, gates at +0/+256/+512
  float wihv[3][2], bihv[3][2], bhhv[3][2], woutv[2];
#pragma unroll
  for (int t = 0; t < 2; ++t) {
    const int j = wv * 32 + t * 16 + c16;
#pragma unroll
    for (int g = 0; g < 3; ++g) {
      wihv[g][t] = w_ih[g * kH + j];
      bihv[g][t] = b_ih[g * kH + j];
      bhhv[g][t] = b_hh[g * kH + j];
    }
    woutv[t] = w_out[j];
  }
  const float bo = b_out[0];

  // init: h0 = 0 -> h_in = e; keep exact h_in in regs, split copy in LDS
  float h_reg[4][4][2];
#pragma unroll
  for (int m = 0; m < 4; ++m)
#pragma unroll
    for (int r = 0; r < 4; ++r)
#pragma unroll
      for (int t = 0; t < 2; ++t) {
        const int rl = m * 16 + grp * 4 + r;
        const int j = wv * 32 + t * 16 + c16;
        const float e = emb[(size_t)(row0 + rl) * kH + j];
        h_reg[m][r][t] = e;
        short hh, hl;
        bsplit(e, hh, hl);
        Ah[rl][j] = hh;
        Al[rl][j] = hl;
      }
  if (tid < kRows) xq[tid] = 0.0f;
  __syncthreads();

  const size_t q_off = (size_t)kBL * kNOut;

  for (int step = 0; step < kNOut; ++step) {
    // ---- MFMA phase: gh[64 rows][wave's 96 gate cols], acc init = b_hh ----
    f32x4 acc[4][2][3];
#pragma unroll
    for (int m = 0; m < 4; ++m)
#pragma unroll
      for (int t = 0; t < 2; ++t)
#pragma unroll
        for (int g = 0; g < 3; ++g) {
          const float b = bhhv[g][t];
          acc[m][t][g] = f32x4{b, b, b, b};
        }

#pragma unroll 2
    for (int kc = 0; kc < 8; ++kc) {
      short8 ah[4], al[4];
#pragma unroll
      for (int m = 0; m < 4; ++m) {
        const int rr = m * 16 + c16;
        const int cc = kc * 32 + grp * 8;
        ah[m] = *reinterpret_cast<const short8*>(&Ah[rr][cc]);
        al[m] = *reinterpret_cast<const short8*>(&Al[rr][cc]);
      }
#pragma unroll
      for (int g = 0; g < 3; ++g)
#pragma unroll
        for (int t = 0; t < 2; ++t) {
          const size_t bidx =
              (size_t)(g * kH + wv * 32 + t * 16 + c16) * kH + kc * 32 + grp * 8;
          const short8 bh = *reinterpret_cast<const short8*>(Bhi + bidx);
          const short8 bl = *reinterpret_cast<const short8*>(Blo + bidx);
#pragma unroll
          for (int m = 0; m < 4; ++m) {
            acc[m][t][g] = __builtin_amdgcn_mfma_f32_16x16x32_bf16(ah[m], bh, acc[m][t][g], 0, 0, 0);
            acc[m][t][g] = __builtin_amdgcn_mfma_f32_16x16x32_bf16(al[m], bh, acc[m][t][g], 0, 0, 0);
            acc[m][t][g] = __builtin_amdgcn_mfma_f32_16x16x32_bf16(ah[m], bl, acc[m][t][g], 0, 0, 0);
          }
        }
    }
    __syncthreads();  // everyone done reading A before we overwrite it

    // ---- gate phase: lane owns rows m*16+grp*4+r (m,r in 0..3), cols j_t ----
    float opart[4][4];
#pragma unroll
    for (int m = 0; m < 4; ++m)
#pragma unroll
      for (int r = 0; r < 4; ++r) opart[m][r] = 0.0f;

#pragma unroll
    for (int m = 0; m < 4; ++m) {
#pragma unroll
      for (int r = 0; r < 4; ++r) {
        const int rl = m * 16 + grp * 4 + r;
        const float x = xq[rl];
#pragma unroll
        for (int t = 0; t < 2; ++t) {
          const int j = wv * 32 + t * 16 + c16;
          const float ghr = acc[m][t][0][r];
          const float ghz = acc[m][t][1][r];
          const float ghn = acc[m][t][2][r];
          const float gr = fmaf(x, wihv[0][t], bihv[0][t]) + ghr;
          const float gz = fmaf(x, wihv[1][t], bihv[1][t]) + ghz;
          const float gni = fmaf(x, wihv[2][t], bihv[2][t]);
          const float rg = 1.0f / (1.0f + __expf(-gr));
          const float zg = 1.0f / (1.0f + __expf(-gz));
          const float ta = gni + rg * ghn;
          const float at = fabsf(ta);
          const float et = __expf(-2.0f * at);
          const float th = copysignf((1.0f - et) / (1.0f + et), ta);
          const float hprev = h_reg[m][r][t];
          const float hn = fmaf(zg, hprev - th, th);  // (1-z)*n + z*hprev
          opart[m][r] = fmaf(hn, woutv[t], opart[m][r]);
          const float hnext = hn + emb[(size_t)(row0 + rl) * kH + j];
          h_reg[m][r][t] = hnext;
          short hh, hl;
          bsplit(hnext, hh, hl);
          Ah[rl][j] = hh;
          Al[rl][j] = hl;
        }
      }
    }

    // reduce o over the 16-lane col group (butterfly); all lanes end identical
#pragma unroll
    for (int m = 0; m < 4; ++m)
#pragma unroll
      for (int r = 0; r < 4; ++r) {
#pragma unroll
        for (int mask = 1; mask < 16; mask <<= 1)
          opart[m][r] += __shfl_xor(opart[m][r], mask, 64);
      }
    // lane c16 writes pair (m,r) = (c16>>2, c16&3) — static-index select
    float ov = opart[0][0];
#pragma unroll
    for (int mm = 0; mm < 4; ++mm)
#pragma unroll
      for (int rr = 0; rr < 4; ++rr)
        if (c16 == mm * 4 + rr) ov = opart[mm][rr];
    osc[(c16 >> 2) * 16 + grp * 4 + (c16 & 3)][wv] = ov;
    __syncthreads();

    // ---- finalize o, q; write outputs and feedback ----
    if (tid < kRows) {
      float s = bo;
#pragma unroll
      for (int w2 = 0; w2 < 8; ++w2) s += osc[tid][w2];
      const float q = s > 0.0f ? 1.0f : -1.0f;
      const size_t gr = (size_t)(row0 + tid);
      out[gr * kNOut + step] = s;
      out[q_off + gr * kNOut + step] = q;
      xq[tid] = q;
    }
    __syncthreads();
  }
}

extern "C" void kernel_launch(void* const* d_in, const int* in_sizes, int n_in,
                              void* d_out, int out_size, void* d_ws, size_t ws_size,
                              hipStream_t stream) {
  (void)in_sizes; (void)n_in; (void)out_size; (void)ws_size;
  const float* emb = (const float*)d_in[0];
  const float* w_ih = (const float*)d_in[1];
  const float* w_hh = (const float*)d_in[2];
  const float* b_ih = (const float*)d_in[3];
  const float* b_hh = (const float*)d_in[4];
  const float* w_out = (const float*)d_in[5];
  const float* b_out = (const float*)d_in[6];

  short* Bhi = (short*)d_ws;                 // 768*256*2 B
  short* Blo = Bhi + kWhh;                   // needs 768 KiB of d_ws total

  split_whh_kernel<<<kWhh / (256 * 4), 256, 0, stream>>>(w_hh, Bhi, Blo);
  rbq_mfma_kernel<<<kBL / kRows, kThreads, 0, stream>>>(
      emb, w_ih, b_ih, b_hh, w_out, b_out, Bhi, Blo, (float*)d_out);
}

// Round 4
// 738.542 us; speedup vs baseline: 7.1100x; 1.0342x over previous
//
#include <hip/hip_runtime.h>
#include <math.h>

namespace {
constexpr int kBL = 16 * 2048;
constexpr int kH = 256;
constexpr int kNOut = 12;
constexpr int kRows = 64;        // rows per block
constexpr int kThreads = 1024;   // 16 waves; wave wv owns gate-cols wv*16..+15 (x3 gates)
constexpr int kS = 264;          // LDS row stride in shorts
constexpr int kWhh = 3 * kH * kH;
}

using short8 = __attribute__((ext_vector_type(8))) short;
using f32x4 = __attribute__((ext_vector_type(4))) float;

__device__ inline void bsplit(float v, short& h, short& l) {
  unsigned u = __float_as_uint(v);
  unsigned rh = u + 0x7FFFu + ((u >> 16) & 1u);   // RNE to bf16
  h = (short)(rh >> 16);
  float hf = __uint_as_float(rh & 0xFFFF0000u);
  float r = v - hf;                                // exact residual
  unsigned u2 = __float_as_uint(r);
  unsigned rl = u2 + 0x7FFFu + ((u2 >> 16) & 1u);
  l = (short)(rl >> 16);
}

// split w_hh [768][256] fp32 -> bf16 hi/lo planes in d_ws
__global__ void split_whh_kernel(const float* __restrict__ w,
                                 short* __restrict__ hi, short* __restrict__ lo) {
  const int i = (blockIdx.x * 256 + threadIdx.x) * 4;
  const float4 v = *reinterpret_cast<const float4*>(w + i);
  short4 h4, l4;
  bsplit(v.x, h4.x, l4.x);
  bsplit(v.y, h4.y, l4.y);
  bsplit(v.z, h4.z, l4.z);
  bsplit(v.w, h4.w, l4.w);
  *reinterpret_cast<short4*>(hi + i) = h4;
  *reinterpret_cast<short4*>(lo + i) = l4;
}

#define MFMA(A, B, C) __builtin_amdgcn_mfma_f32_16x16x32_bf16((A), (B), (C), 0, 0, 0)

__global__ __launch_bounds__(kThreads, 4)
void rbq_mfma3_kernel(const float* __restrict__ emb,    // [BL][256]
                      const float* __restrict__ w_ih,   // [768]
                      const float* __restrict__ b_ih,   // [768]
                      const float* __restrict__ b_hh,   // [768]
                      const float* __restrict__ w_out,  // [256]
                      const float* __restrict__ b_out,  // [1]
                      const short* __restrict__ Bh,     // [768][256] bf16 hi
                      const short* __restrict__ Bl,     // [768][256] bf16 lo
                      float* __restrict__ out) {        // [2][BL][12]
  __shared__ short Ah[kRows][kS];   // h_in hi (MFMA reads / gate writes, 2 barriers)
  __shared__ short Al[kRows][kS];   // h_in lo
  __shared__ float osc[kRows][17];  // per-wave o partials (pad 17: conflict-free)
  __shared__ float xq[kRows];       // quantized feedback

  const int tid = threadIdx.x;
  const int lane = tid & 63;
  const int wv = __builtin_amdgcn_readfirstlane(tid >> 6);  // 0..15
  const int grp = lane >> 4;
  const int c16 = lane & 15;
  const int row0 = blockIdx.x * kRows;
  const int j = wv * 16 + c16;      // this lane's H column

  // per-lane gate constants (round-2 exact numerics: biases NOT folded into acc)
  const float wihr = w_ih[j], wihz = w_ih[kH + j], wihn = w_ih[2 * kH + j];
  const float bihr = b_ih[j], bihz = b_ih[kH + j], bihn = b_ih[2 * kH + j];
  const float bhhr = b_hh[j], bhhz = b_hh[kH + j], bhhn = b_hh[2 * kH + j];
  const float wo = w_out[j];
  const float bo = b_out[0];
  const size_t q_off = (size_t)kBL * kNOut;

  // init: h0 = 0 -> h_in = e; exact h_in in regs, split copy in LDS
  float h_reg[4][4];
#pragma unroll
  for (int m = 0; m < 4; ++m)
#pragma unroll
    for (int r = 0; r < 4; ++r) {
      const int rl = m * 16 + grp * 4 + r;
      const float e = emb[(size_t)(row0 + rl) * kH + j];
      h_reg[m][r] = e;
      short hh, hl;
      bsplit(e, hh, hl);
      Ah[rl][j] = hh;
      Al[rl][j] = hl;
    }
  if (tid < kRows) xq[tid] = 0.0f;
  __syncthreads();

  for (int step = 0; step < kNOut; ++step) {
    // ---- MFMA phase: gh for this wave's 16 cols x 3 gates, all 64 rows ----
    f32x4 acc[4][3];
#pragma unroll
    for (int m = 0; m < 4; ++m) {
      acc[m][0] = f32x4{bhhr, bhhr, bhhr, bhhr};
      acc[m][1] = f32x4{bhhz, bhhz, bhhz, bhhz};
      acc[m][2] = f32x4{bhhn, bhhn, bhhn, bhhn};
    }

#pragma unroll 1
    for (int kc = 0; kc < 8; ++kc) {
      const int ko = kc * 32 + grp * 8;
      short8 bh[3], bl[3];
#pragma unroll
      for (int g = 0; g < 3; ++g) {
        const size_t base = (size_t)(g * kH + j) * kH + ko;
        bh[g] = *reinterpret_cast<const short8*>(Bh + base);
        bl[g] = *reinterpret_cast<const short8*>(Bl + base);
      }
#pragma unroll
      for (int m = 0; m < 4; ++m) {
        const short8 ah = *reinterpret_cast<const short8*>(&Ah[m * 16 + c16][ko]);
        const short8 al = *reinterpret_cast<const short8*>(&Al[m * 16 + c16][ko]);
        // per-acc pass order identical to round 2: ah*bh, al*bh, ah*bl
#pragma unroll
        for (int g = 0; g < 3; ++g) acc[m][g] = MFMA(ah, bh[g], acc[m][g]);
#pragma unroll
        for (int g = 0; g < 3; ++g) acc[m][g] = MFMA(al, bh[g], acc[m][g]);
#pragma unroll
        for (int g = 0; g < 3; ++g) acc[m][g] = MFMA(ah, bl[g], acc[m][g]);
      }
    }
    __syncthreads();  // all A reads done; xq(step-1) visible

    // ---- gate phase: lane owns rows m*16+grp*4+r at col j; writes A(next) ----
    float opart[4][4];
#pragma unroll
    for (int m = 0; m < 4; ++m) {
#pragma unroll
      for (int r = 0; r < 4; ++r) {
        const int rl = m * 16 + grp * 4 + r;
        const float x = xq[rl];
        const float ghr = acc[m][0][r];
        const float ghz = acc[m][1][r];
        const float ghn = acc[m][2][r];
        const float gr = fmaf(x, wihr, bihr) + ghr;   // round-2 exact expr
        const float gz = fmaf(x, wihz, bihz) + ghz;
        const float gni = fmaf(x, wihn, bihn);
        const float rg = 1.0f / (1.0f + __expf(-gr));
        const float zg = 1.0f / (1.0f + __expf(-gz));
        const float ta = gni + rg * ghn;
        const float at = fabsf(ta);
        const float et = __expf(-2.0f * at);
        const float th = copysignf((1.0f - et) / (1.0f + et), ta);
        const float hn = fmaf(zg, h_reg[m][r] - th, th);   // (1-z)*n + z*h_in
        opart[m][r] = hn * wo;
        // next h_in = h_new + e (e re-read: exact fp32, saves 16 VGPR)
        const float hnext = hn + emb[(size_t)(row0 + rl) * kH + j];
        h_reg[m][r] = hnext;
        short hh, hl;
        bsplit(hnext, hh, hl);
        Ah[rl][j] = hh;
        Al[rl][j] = hl;
      }
    }

    // exact-fp32 o: butterfly over the 16 cols of this wave
#pragma unroll
    for (int m = 0; m < 4; ++m)
#pragma unroll
      for (int r = 0; r < 4; ++r) {
#pragma unroll
        for (int mask = 1; mask < 16; mask <<= 1)
          opart[m][r] += __shfl_xor(opart[m][r], mask, 16);
      }
    if (c16 == 0) {
#pragma unroll
      for (int m = 0; m < 4; ++m)
#pragma unroll
        for (int r = 0; r < 4; ++r)
          osc[m * 16 + grp * 4 + r][wv] = opart[m][r];
    }
    __syncthreads();  // osc ready; A(next) complete

    // ---- finalize o(step), q, feedback — overlaps next MFMA phase ----
    if (tid < kRows) {
      float s = bo;
#pragma unroll
      for (int w2 = 0; w2 < 16; ++w2) s += osc[tid][w2];
      const float q = s > 0.0f ? 1.0f : -1.0f;
      const size_t gr = (size_t)(row0 + tid);
      out[gr * kNOut + step] = s;
      out[q_off + gr * kNOut + step] = q;
      xq[tid] = q;
    }
  }
}

extern "C" void kernel_launch(void* const* d_in, const int* in_sizes, int n_in,
                              void* d_out, int out_size, void* d_ws, size_t ws_size,
                              hipStream_t stream) {
  (void)in_sizes; (void)n_in; (void)out_size; (void)ws_size;
  const float* emb = (const float*)d_in[0];
  const float* w_ih = (const float*)d_in[1];
  const float* w_hh = (const float*)d_in[2];
  const float* b_ih = (const float*)d_in[3];
  const float* b_hh = (const float*)d_in[4];
  const float* w_out = (const float*)d_in[5];
  const float* b_out = (const float*)d_in[6];

  short* Bh = (short*)d_ws;                  // [768][256] bf16 hi
  short* Bl = Bh + kWhh;                     // [768][256] bf16 lo (768 KiB total)

  split_whh_kernel<<<kWhh / (256 * 4), 256, 0, stream>>>(w_hh, Bh, Bl);
  rbq_mfma3_kernel<<<kBL / kRows, kThreads, 0, stream>>>(
      emb, w_ih, b_ih, b_hh, w_out, b_out, Bh, Bl, (float*)d_out);
}